// Round 19
// baseline (5843.595 us; speedup 1.0000x reference)
//
#include <hip/hip_runtime.h>
#include <hip/hip_bf16.h>

#define TT 2048
#define HH 1024
#define GH 4096

__device__ __forceinline__ float sigm(float x){ return 1.0f / (1.0f + __expf(-x)); }
__device__ __forceinline__ float bflo(unsigned v){ return __uint_as_float(v << 16); }
__device__ __forceinline__ float bfhi(unsigned v){ return __uint_as_float(v & 0xffff0000u); }
__device__ __forceinline__ unsigned short f2bu(float x){
  __hip_bfloat16 b = __float2bfloat16(x);
  return *reinterpret_cast<unsigned short*>(&b);
}
// barrier with LDS-only drain: h_lds writes commit, but vmem (publish stores,
// gx prefetch) stays in flight -- removes the vmcnt(0) drain __syncthreads adds.
__device__ __forceinline__ void bar_lds(){
  asm volatile("s_waitcnt lgkmcnt(0)\n\ts_barrier" ::: "memory");
}
// bare barrier: all LDS reads before it are data-dependency-complete.
__device__ __forceinline__ void bar_nowait(){
  asm volatile("s_barrier" ::: "memory");
}
// explicit vmem drain (placed where the queue is naturally empty).
__device__ __forceinline__ void drain_vm(){
  asm volatile("s_waitcnt vmcnt(0)" ::: "memory");
}

#define SCANBLK 64
#define NTH 512
#define HSTRIDE 130
#define ROWU 257          // uint2 units per weight row (256 + 1 pad)
#define NREP 8

// GEMM tile params (validated r3-r18)
#define BM 128
#define BN 64
#define BK 32
#define GEMMBLK 1024      // 16 bm x 64 bn

// -------- Fused kernel: blocks 0..63 = persistent scan; 64..1087 = fp32 GEMM --------
__global__ __launch_bounds__(NTH) void fused_lstm(
    const int* __restrict__ tokens,
    const float* __restrict__ emb,
    const float* __restrict__ Wih,
    const float* __restrict__ bih,
    const float* __restrict__ bhh,
    const float* __restrict__ Whh,
    unsigned long long* slots,     // [NREP][2][1024] {tag<<32 | fp32 h}
    int* cnt,                      // [16] row-block completion counters (target 64)
    float* gx,                     // [2048][4096] fp32
    float* __restrict__ out)       // [2048] fp32 = h ; c
{
  extern __shared__ __align__(16) unsigned dynls[];
  const int tid = threadIdx.x;

  if (blockIdx.x >= SCANBLK) {
    // ================= GEMM path (validated r18) =================
    float* As = (float*)dynls;            // [128][33]
    float* Bs = As + 128*33;              // [64][33]
    int* tok_s = (int*)(Bs + 64*33);      // [128]

    const int gb = blockIdx.x - SCANBLK;  // 0..1023
    const int bn = gb & 63, bm = gb >> 6;
    const int m0 = bm*BM, n0 = bn*BN;

    if (tid < BM) tok_s[tid] = tokens[m0 + tid];
    __syncthreads();

    const int tm = tid >> 4;   // valid for tid<256
    const int tn = tid & 15;

    float acc[8][4];
    #pragma unroll
    for (int i = 0; i < 8; ++i)
      #pragma unroll
      for (int j = 0; j < 4; ++j) acc[i][j] = 0.0f;

    for (int k0 = 0; k0 < HH; k0 += BK) {
      if (tid < 256) {
        for (int idx = tid; idx < BM*BK; idx += 256) {
          int r = idx >> 5, c = idx & 31;
          As[r*33 + c] = emb[(size_t)tok_s[r]*HH + k0 + c];
        }
        for (int idx = tid; idx < BN*BK; idx += 256) {
          int r = idx >> 5, c = idx & 31;
          Bs[r*33 + c] = Wih[(size_t)(n0 + r)*HH + k0 + c];
        }
      }
      __syncthreads();
      if (tid < 256) {
        #pragma unroll
        for (int k = 0; k < BK; ++k) {
          float a[8], bb[4];
          #pragma unroll
          for (int i = 0; i < 8; ++i) a[i] = As[(tm*8 + i)*33 + k];
          #pragma unroll
          for (int j = 0; j < 4; ++j) bb[j] = Bs[(tn*4 + j)*33 + k];
          #pragma unroll
          for (int i = 0; i < 8; ++i)
            #pragma unroll
            for (int j = 0; j < 4; ++j)
              acc[i][j] = fmaf(a[i], bb[j], acc[i][j]);
        }
      }
      __syncthreads();
    }

    if (tid < 256) {
      float bias[4];
      #pragma unroll
      for (int j = 0; j < 4; ++j) {
        int col = n0 + tn*4 + j;
        bias[j] = bih[col] + bhh[col];
      }
      #pragma unroll
      for (int i = 0; i < 8; ++i) {
        int r = m0 + tm*8 + i;
        #pragma unroll
        for (int j = 0; j < 4; ++j)
          gx[(size_t)r*GH + (n0 + tn*4 + j)] = acc[i][j] + bias[j];
      }
    }
    __syncthreads();                    // pre-barrier vmcnt drains the gx stores
    if (tid == 0)
      __hip_atomic_fetch_add(&cnt[bm], 1, __ATOMIC_RELEASE, __HIP_MEMORY_SCOPE_AGENT);
    return;
  }

  // ================= scan path (r18 math; soft barriers) =================
  unsigned* wdw = dynls;                // 64*ROWU uint2 (bf16 weights)
  __shared__ float h_lds[32*HSTRIDE];

  const int b = blockIdx.x;
  const int s  = tid & 31;        // lane within group / col segment
  const int G  = tid >> 5;        // group 0..15 = local output index
  const int o  = (b << 4) + G;    // owned output

  for (int r = 0; r < 64; ++r) {
    const int Gr = r >> 2, g = r & 3;
    const int jrow = (g << 10) + (b << 4) + Gr;
    const int c0 = tid * 2;
    const float2 f2 = *(const float2*)(Whh + (size_t)jrow*HH + c0);
    const unsigned pk = (unsigned)f2bu(f2.x) | ((unsigned)f2bu(f2.y) << 16);
    const int sT = c0 >> 5, j2 = (c0 & 31) >> 2, d = (c0 >> 1) & 1;
    wdw[r*(2*ROWU) + (j2*32 + sT)*2 + d] = pk;
  }
  for (int i = tid; i < 32*HSTRIDE; i += NTH) h_lds[i] = 0.0f;   // h(0)=0

  int rdy = 0;
  while (__hip_atomic_load(&cnt[0], __ATOMIC_ACQUIRE, __HIP_MEMORY_SCOPE_AGENT) < 64) {}
  rdy = 1;

  float cst = 0.0f;
  float g4[4];
  #pragma unroll
  for (int g = 0; g < 4; ++g) g4[g] = gx[(g << 10) + o];   // t=0

  const int i0 = tid, i1 = tid + 512;
  const int p0 = (i0 >> 5)*HSTRIDE + (i0 & 31);
  const int p1 = (i1 >> 5)*HSTRIDE + (i1 & 31);
  const unsigned long long* prep = slots + (size_t)((b & (NREP-1)) * 2) * 1024;
  __syncthreads();

  const uint2* wld2 = (const uint2*)wdw;

  for (int t = 0; t < TT; ++t) {
    float ng[4] = {0.f, 0.f, 0.f, 0.f};
    if (t + 1 < TT) {
      const int rb = (t+1) >> 7;
      if (rdy <= rb) {
        while (__hip_atomic_load(&cnt[rb], __ATOMIC_ACQUIRE, __HIP_MEMORY_SCOPE_AGENT) < 64) {}
        rdy = rb + 1;
      }
      #pragma unroll
      for (int g = 0; g < 4; ++g)
        ng[g] = gx[(size_t)(t+1)*GH + (g << 10) + o];
    }

    if (t > 0) {
      const unsigned long long* sb = prep + (size_t)(t & 1) * 1024;
      const unsigned tg = (unsigned)t;
      unsigned long long v0 = __hip_atomic_load(&sb[i0], __ATOMIC_RELAXED, __HIP_MEMORY_SCOPE_AGENT);
      unsigned long long v1 = __hip_atomic_load(&sb[i1], __ATOMIC_RELAXED, __HIP_MEMORY_SCOPE_AGENT);
      while ((unsigned)(v0 >> 32) != tg)
        v0 = __hip_atomic_load(&sb[i0], __ATOMIC_RELAXED, __HIP_MEMORY_SCOPE_AGENT);
      while ((unsigned)(v1 >> 32) != tg)
        v1 = __hip_atomic_load(&sb[i1], __ATOMIC_RELAXED, __HIP_MEMORY_SCOPE_AGENT);
      h_lds[p0] = __uint_as_float((unsigned)v0);
      h_lds[p1] = __uint_as_float((unsigned)v1);
      bar_lds();                     // lgkmcnt(0)+s_barrier: vmem stays in flight
    }

    float a0 = 0.f, a1 = 0.f, a2 = 0.f, a3 = 0.f;
    const float* hseg = h_lds + s*HSTRIDE;
    #pragma unroll
    for (int j2 = 0; j2 < 8; ++j2) {
      const float2 hA = *(const float2*)(hseg + 4*j2);
      const float2 hB = *(const float2*)(hseg + 4*j2 + 2);
      const uint2 w0 = wld2[(G*4 + 0)*ROWU + j2*32 + s];
      const uint2 w1 = wld2[(G*4 + 1)*ROWU + j2*32 + s];
      const uint2 w2 = wld2[(G*4 + 2)*ROWU + j2*32 + s];
      const uint2 w3 = wld2[(G*4 + 3)*ROWU + j2*32 + s];
      a0 = fmaf(bflo(w0.x), hA.x, a0); a0 = fmaf(bfhi(w0.x), hA.y, a0);
      a0 = fmaf(bflo(w0.y), hB.x, a0); a0 = fmaf(bfhi(w0.y), hB.y, a0);
      a1 = fmaf(bflo(w1.x), hA.x, a1); a1 = fmaf(bfhi(w1.x), hA.y, a1);
      a1 = fmaf(bflo(w1.y), hB.x, a1); a1 = fmaf(bfhi(w1.y), hB.y, a1);
      a2 = fmaf(bflo(w2.x), hA.x, a2); a2 = fmaf(bfhi(w2.x), hA.y, a2);
      a2 = fmaf(bflo(w2.y), hB.x, a2); a2 = fmaf(bfhi(w2.y), hB.y, a2);
      a3 = fmaf(bflo(w3.x), hA.x, a3); a3 = fmaf(bfhi(w3.x), hA.y, a3);
      a3 = fmaf(bflo(w3.y), hB.x, a3); a3 = fmaf(bfhi(w3.y), hB.y, a3);
    }
    #pragma unroll
    for (int m = 1; m <= 16; m <<= 1) {
      a0 += __shfl_xor(a0, m);
      a1 += __shfl_xor(a1, m);
      a2 += __shfl_xor(a2, m);
      a3 += __shfl_xor(a3, m);
    }

    const float xi = a0 + g4[0];
    const float xf = a1 + g4[1];
    const float xg = a2 + g4[2];
    const float xo = a3 + g4[3];
    cst = sigm(xf)*cst + sigm(xi)*tanhf(xg);
    const float hnew = sigm(xo)*tanhf(cst);

    // drain vmem HERE (queue ~empty: prev publish 1 step old, ng loads landed).
    // Guarantees publish(t) committed before publish(t+2) to the same slot.
    drain_vm();

    if (t == TT-1) {
      if (s == 0) {
        out[o]        = hnew;
        out[1024 + o] = cst;
      }
    } else {
      if (s == 0) {
        const unsigned long long pv =
            (((unsigned long long)(unsigned)(t+1)) << 32) |
            (unsigned long long)__float_as_uint(hnew);
        const int nxt = (t+1) & 1;
        #pragma unroll
        for (int r = 0; r < NREP; ++r)
          __hip_atomic_store(&slots[(size_t)(r*2 + nxt)*1024 + o], pv,
                             __ATOMIC_RELAXED, __HIP_MEMORY_SCOPE_AGENT);
      }
      #pragma unroll
      for (int g = 0; g < 4; ++g) g4[g] = ng[g];
    }
    bar_nowait();                    // protect h_lds; no vmem drain
  }
}

// -------- fallbacks (separate kernels; used only if attribute/ws fails) --------
__global__ __launch_bounds__(256) void gemm_simple(
    const int* __restrict__ tokens,
    const float* __restrict__ emb,
    const float* __restrict__ Wih,
    const float* __restrict__ bih,
    const float* __restrict__ bhh,
    float* __restrict__ gx)
{
  __shared__ float As[BM][BK+1];
  __shared__ float Bs[BN][BK+1];
  __shared__ int tok_s[BM];

  const int tid = threadIdx.x;
  const int bn = blockIdx.x;
  const int bm = blockIdx.y;
  const int m0 = bm*BM, n0 = bn*BN;

  if (tid < BM) tok_s[tid] = tokens[m0 + tid];
  __syncthreads();

  const int tm = tid >> 4;
  const int tn = tid & 15;

  float acc[8][4];
  #pragma unroll
  for (int i = 0; i < 8; ++i)
    #pragma unroll
    for (int j = 0; j < 4; ++j) acc[i][j] = 0.0f;

  for (int k0 = 0; k0 < HH; k0 += BK) {
    for (int idx = tid; idx < BM*BK; idx += 256) {
      int r = idx >> 5, c = idx & 31;
      As[r][c] = emb[(size_t)tok_s[r]*HH + k0 + c];
    }
    for (int idx = tid; idx < BN*BK; idx += 256) {
      int r = idx >> 5, c = idx & 31;
      Bs[r][c] = Wih[(size_t)(n0 + r)*HH + k0 + c];
    }
    __syncthreads();
    #pragma unroll
    for (int k = 0; k < BK; ++k) {
      float a[8], bb[4];
      #pragma unroll
      for (int i = 0; i < 8; ++i) a[i] = As[tm*8 + i][k];
      #pragma unroll
      for (int j = 0; j < 4; ++j) bb[j] = Bs[tn*4 + j][k];
      #pragma unroll
      for (int i = 0; i < 8; ++i)
        #pragma unroll
        for (int j = 0; j < 4; ++j)
          acc[i][j] = fmaf(a[i], bb[j], acc[i][j]);
    }
    __syncthreads();
  }

  float bias[4];
  #pragma unroll
  for (int j = 0; j < 4; ++j) {
    int col = n0 + tn*4 + j;
    bias[j] = bih[col] + bhh[col];
  }
  #pragma unroll
  for (int i = 0; i < 8; ++i) {
    int r = m0 + tm*8 + i;
    #pragma unroll
    for (int j = 0; j < 4; ++j)
      gx[(size_t)r*GH + (n0 + tn*4 + j)] = acc[i][j] + bias[j];
  }
}

__global__ __launch_bounds__(NTH, 2) void lstm_scan_reg(
    const float* __restrict__ gx,
    const float* __restrict__ Whh,
    unsigned long long* slots,
    float* __restrict__ out)
{
  const int b = blockIdx.x;
  const int tid = threadIdx.x;
  const int s  = tid & 31;
  const int rg = tid >> 5;

  __shared__ float h_lds[32*HSTRIDE];
  __shared__ float gates_lds[64];

  float w[128];
  #pragma unroll
  for (int a = 0; a < 4; ++a) {
    int row = rg*4 + a;
    int jrow = ((row >> 4) << 10) + (b << 4) + (row & 15);
    const float* wr = Whh + (size_t)jrow*HH + s*32;
    #pragma unroll
    for (int q = 0; q < 8; ++q) {
      float4 f4 = ((const float4*)wr)[q];
      w[a*32 + q*4 + 0] = f4.x; w[a*32 + q*4 + 1] = f4.y;
      w[a*32 + q*4 + 2] = f4.z; w[a*32 + q*4 + 3] = f4.w;
    }
  }

  for (int i = tid; i < 32*HSTRIDE; i += NTH) h_lds[i] = 0.0f;
  float c0 = 0.0f, c1 = 0.0f;
  const int i0 = tid, i1 = tid + 512;
  const int p0 = (i0 >> 5)*HSTRIDE + (i0 & 31);
  const int p1 = (i1 >> 5)*HSTRIDE + (i1 & 31);
  const int myrow = rg*4 + s;
  const int myj = ((myrow >> 4) << 10) + (b << 4) + (myrow & 15);
  __syncthreads();

  for (int t = 0; t < TT; ++t) {
    float gxv = 0.0f;
    if (s < 4) gxv = gx[(size_t)t*GH + myj];

    if (t > 0) {
      const unsigned long long* sb = slots + (size_t)(t & 1)*1024;
      const unsigned tg = (unsigned)t;
      unsigned long long v0 = __hip_atomic_load(&sb[i0], __ATOMIC_RELAXED, __HIP_MEMORY_SCOPE_AGENT);
      unsigned long long v1 = __hip_atomic_load(&sb[i1], __ATOMIC_RELAXED, __HIP_MEMORY_SCOPE_AGENT);
      while ((unsigned)(v0 >> 32) != tg)
        v0 = __hip_atomic_load(&sb[i0], __ATOMIC_RELAXED, __HIP_MEMORY_SCOPE_AGENT);
      while ((unsigned)(v1 >> 32) != tg)
        v1 = __hip_atomic_load(&sb[i1], __ATOMIC_RELAXED, __HIP_MEMORY_SCOPE_AGENT);
      h_lds[p0] = __uint_as_float((unsigned)v0);
      h_lds[p1] = __uint_as_float((unsigned)v1);
      __syncthreads();
    }

    float acc0 = 0.f, acc1 = 0.f, acc2 = 0.f, acc3 = 0.f;
    const float* hseg = h_lds + s*HSTRIDE;
    #pragma unroll
    for (int c2 = 0; c2 < 16; ++c2) {
      float2 hv = *(const float2*)(hseg + 2*c2);
      acc0 = fmaf(w[0*32+2*c2], hv.x, acc0); acc0 = fmaf(w[0*32+2*c2+1], hv.y, acc0);
      acc1 = fmaf(w[1*32+2*c2], hv.x, acc1); acc1 = fmaf(w[1*32+2*c2+1], hv.y, acc1);
      acc2 = fmaf(w[2*32+2*c2], hv.x, acc2); acc2 = fmaf(w[2*32+2*c2+1], hv.y, acc2);
      acc3 = fmaf(w[3*32+2*c2], hv.x, acc3); acc3 = fmaf(w[3*32+2*c2+1], hv.y, acc3);
    }
    #pragma unroll
    for (int m = 1; m <= 16; m <<= 1) {
      acc0 += __shfl_xor(acc0, m);
      acc1 += __shfl_xor(acc1, m);
      acc2 += __shfl_xor(acc2, m);
      acc3 += __shfl_xor(acc3, m);
    }
    if (s < 4) {
      float v = acc0;
      if (s == 1) v = acc1; else if (s == 2) v = acc2; else if (s == 3) v = acc3;
      gates_lds[rg*4 + s] = v + gxv;
    }
    __syncthreads();

    if (tid < 8) {
      int n0 = tid*2, n1 = n0 + 1;
      float xi0 = gates_lds[n0],    xi1 = gates_lds[n1];
      float xf0 = gates_lds[16+n0], xf1 = gates_lds[16+n1];
      float xg0 = gates_lds[32+n0], xg1 = gates_lds[32+n1];
      float xo0 = gates_lds[48+n0], xo1 = gates_lds[48+n1];
      c0 = sigm(xf0)*c0 + sigm(xi0)*tanhf(xg0);
      c1 = sigm(xf1)*c1 + sigm(xi1)*tanhf(xg1);
      float h0 = sigm(xo0)*tanhf(c0);
      float h1 = sigm(xo1)*tanhf(c1);
      if (t == TT-1) {
        out[(b<<4)+n0]      = h0;
        out[(b<<4)+n1]      = h1;
        out[1024+(b<<4)+n0] = c0;
        out[1024+(b<<4)+n1] = c1;
      } else {
        unsigned long long* db = slots + (size_t)((t+1)&1)*1024;
        unsigned long long tg = ((unsigned long long)(unsigned)(t+1)) << 32;
        __hip_atomic_store(&db[(b<<4)+n0], tg | (unsigned long long)__float_as_uint(h0),
                           __ATOMIC_RELAXED, __HIP_MEMORY_SCOPE_AGENT);
        __hip_atomic_store(&db[(b<<4)+n1], tg | (unsigned long long)__float_as_uint(h1),
                           __ATOMIC_RELAXED, __HIP_MEMORY_SCOPE_AGENT);
      }
    }
  }
}

__global__ void zero_out(float* out){
  int i = blockIdx.x*256 + threadIdx.x;
  if (i < 2048) out[i] = 0.0f;
}

extern "C" void kernel_launch(void* const* d_in, const int* in_sizes, int n_in,
                              void* d_out, int out_size, void* d_ws, size_t ws_size,
                              hipStream_t stream) {
  (void)in_sizes; (void)n_in; (void)out_size;
  const int* tokens = (const int*)d_in[0];
  const float* emb  = (const float*)d_in[1];
  const float* Wih  = (const float*)d_in[2];
  const float* Whh  = (const float*)d_in[3];
  const float* bih  = (const float*)d_in[4];
  const float* bhh  = (const float*)d_in[5];
  float* out = (float*)d_out;

  const size_t gxBytes   = (size_t)TT*GH*sizeof(float);
  const size_t slotBytes = (size_t)NREP*2*1024*8;   // 131072
  const size_t ctrlBytes = slotBytes + 2048;        // + cnt[16] (padded)

  unsigned long long* slots = (unsigned long long*)d_ws;
  int* cnt  = (int*)((char*)d_ws + slotBytes);
  float* gx = (float*)((char*)d_ws + ctrlBytes);

  if (ws_size < ctrlBytes + gxBytes) {
    if (ws_size >= 16384 + gxBytes) {
      float* gx1 = (float*)((char*)d_ws + 16384);
      hipMemsetAsync(d_ws, 0, 16384, stream);
      gemm_simple<<<dim3(64,16), dim3(256), 0, stream>>>(tokens, emb, Wih, bih, bhh, gx1);
      lstm_scan_reg<<<dim3(SCANBLK), dim3(NTH), 0, stream>>>(gx1, Whh, slots, out);
    } else {
      zero_out<<<dim3(8), dim3(256), 0, stream>>>(out);
    }
    return;
  }

  hipMemsetAsync(d_ws, 0, ctrlBytes, stream);

  const int dynBytes = 64 * (2*ROWU) * 4;   // 131584 B (scan weights / gemm tiles overlay)
  hipError_t e = hipFuncSetAttribute((const void*)fused_lstm,
                                     hipFuncAttributeMaxDynamicSharedMemorySize,
                                     dynBytes);
  if (e == hipSuccess) {
    fused_lstm<<<dim3(SCANBLK + GEMMBLK), dim3(NTH), dynBytes, stream>>>(
        tokens, emb, Wih, bih, bhh, Whh, slots, cnt, gx, out);
  } else {
    (void)hipGetLastError();
    gemm_simple<<<dim3(64,16), dim3(256), 0, stream>>>(tokens, emb, Wih, bih, bhh, gx);
    lstm_scan_reg<<<dim3(SCANBLK), dim3(NTH), 0, stream>>>(gx, Whh, slots, out);
  }
}

// Round 20
// 5751.514 us; speedup vs baseline: 1.0160x; 1.0160x over previous
//
#include <hip/hip_runtime.h>
#include <hip/hip_bf16.h>

#define TT 2048
#define HH 1024
#define GH 4096

__device__ __forceinline__ float sigm(float x){ return 1.0f / (1.0f + __expf(-x)); }
__device__ __forceinline__ float bflo(unsigned v){ return __uint_as_float(v << 16); }
__device__ __forceinline__ float bfhi(unsigned v){ return __uint_as_float(v & 0xffff0000u); }
__device__ __forceinline__ unsigned short f2bu(float x){
  __hip_bfloat16 b = __float2bfloat16(x);
  return *reinterpret_cast<unsigned short*>(&b);
}

#define SCANBLK 64
#define NTH 512
#define HSTRIDE 130
#define ROWU 257          // uint2 units per weight row (256 + 1 pad)
#define NREP 8

// GEMM tile params (validated r3-r18)
#define BM 128
#define BN 64
#define BK 32
#define GEMMBLK 1024      // 16 bm x 64 bn

// -------- Fused kernel: blocks 0..63 = persistent scan (r18-exact);
//          blocks 64..1087 = fp32 GEMM producing gx row-blocks, signaled via cnt[bm].
__global__ __launch_bounds__(NTH) void fused_lstm(
    const int* __restrict__ tokens,
    const float* __restrict__ emb,
    const float* __restrict__ Wih,
    const float* __restrict__ bih,
    const float* __restrict__ bhh,
    const float* __restrict__ Whh,
    unsigned long long* slots,     // [NREP][2][1024] {tag<<32 | fp32 h}
    int* cnt,                      // [16] row-block completion counters (target 64)
    float* gx,                     // [2048][4096] fp32
    float* __restrict__ out)       // [2048] fp32 = h ; c
{
  extern __shared__ __align__(16) unsigned dynls[];
  const int tid = threadIdx.x;

  if (blockIdx.x >= SCANBLK) {
    // ================= GEMM path (validated r18) =================
    float* As = (float*)dynls;            // [128][33]
    float* Bs = As + 128*33;              // [64][33]
    int* tok_s = (int*)(Bs + 64*33);      // [128]

    const int gb = blockIdx.x - SCANBLK;  // 0..1023
    const int bn = gb & 63, bm = gb >> 6;
    const int m0 = bm*BM, n0 = bn*BN;

    if (tid < BM) tok_s[tid] = tokens[m0 + tid];
    __syncthreads();

    const int tm = tid >> 4;   // valid for tid<256
    const int tn = tid & 15;

    float acc[8][4];
    #pragma unroll
    for (int i = 0; i < 8; ++i)
      #pragma unroll
      for (int j = 0; j < 4; ++j) acc[i][j] = 0.0f;

    for (int k0 = 0; k0 < HH; k0 += BK) {
      if (tid < 256) {
        for (int idx = tid; idx < BM*BK; idx += 256) {
          int r = idx >> 5, c = idx & 31;
          As[r*33 + c] = emb[(size_t)tok_s[r]*HH + k0 + c];
        }
        for (int idx = tid; idx < BN*BK; idx += 256) {
          int r = idx >> 5, c = idx & 31;
          Bs[r*33 + c] = Wih[(size_t)(n0 + r)*HH + k0 + c];
        }
      }
      __syncthreads();
      if (tid < 256) {
        #pragma unroll
        for (int k = 0; k < BK; ++k) {
          float a[8], bb[4];
          #pragma unroll
          for (int i = 0; i < 8; ++i) a[i] = As[(tm*8 + i)*33 + k];
          #pragma unroll
          for (int j = 0; j < 4; ++j) bb[j] = Bs[(tn*4 + j)*33 + k];
          #pragma unroll
          for (int i = 0; i < 8; ++i)
            #pragma unroll
            for (int j = 0; j < 4; ++j)
              acc[i][j] = fmaf(a[i], bb[j], acc[i][j]);
        }
      }
      __syncthreads();
    }

    if (tid < 256) {
      float bias[4];
      #pragma unroll
      for (int j = 0; j < 4; ++j) {
        int col = n0 + tn*4 + j;
        bias[j] = bih[col] + bhh[col];
      }
      #pragma unroll
      for (int i = 0; i < 8; ++i) {
        int r = m0 + tm*8 + i;
        #pragma unroll
        for (int j = 0; j < 4; ++j)
          gx[(size_t)r*GH + (n0 + tn*4 + j)] = acc[i][j] + bias[j];
      }
    }
    __syncthreads();                    // pre-barrier vmcnt drains the gx stores
    if (tid == 0)
      __hip_atomic_fetch_add(&cnt[bm], 1, __ATOMIC_RELEASE, __HIP_MEMORY_SCOPE_AGENT);
    return;
  }

  // ================= scan path (r18-exact, NREP=8) =================
  unsigned* wdw = dynls;                // 64*ROWU uint2 (bf16 weights)
  __shared__ float h_lds[32*HSTRIDE];

  const int b = blockIdx.x;
  const int s  = tid & 31;        // lane within group / col segment
  const int G  = tid >> 5;        // group 0..15 = local output index
  const int o  = (b << 4) + G;    // owned output

  // stage weights once: storage row r=G*4+g <- Whh[g*1024 + b*16 + G]
  for (int r = 0; r < 64; ++r) {
    const int Gr = r >> 2, g = r & 3;
    const int jrow = (g << 10) + (b << 4) + Gr;
    const int c0 = tid * 2;
    const float2 f2 = *(const float2*)(Whh + (size_t)jrow*HH + c0);
    const unsigned pk = (unsigned)f2bu(f2.x) | ((unsigned)f2bu(f2.y) << 16);
    const int sT = c0 >> 5, j2 = (c0 & 31) >> 2, d = (c0 >> 1) & 1;
    wdw[r*(2*ROWU) + (j2*32 + sT)*2 + d] = pk;
  }
  for (int i = tid; i < 32*HSTRIDE; i += NTH) h_lds[i] = 0.0f;   // h(0)=0

  int rdy = 0;                    // highest gx row-block known complete
  while (__hip_atomic_load(&cnt[0], __ATOMIC_ACQUIRE, __HIP_MEMORY_SCOPE_AGENT) < 64) {}
  rdy = 1;

  float cst = 0.0f;
  float g4[4];
  #pragma unroll
  for (int g = 0; g < 4; ++g) g4[g] = gx[(g << 10) + o];   // t=0

  const int i0 = tid, i1 = tid + 512;
  const int p0 = (i0 >> 5)*HSTRIDE + (i0 & 31);
  const int p1 = (i1 >> 5)*HSTRIDE + (i1 & 31);
  const unsigned long long* prep = slots + (size_t)((b & (NREP-1)) * 2) * 1024;
  __syncthreads();

  const uint2* wld2 = (const uint2*)wdw;

  for (int t = 0; t < TT; ++t) {
    // gx readiness for the t+1 prefetch (amortized: 1 check per 128 steps)
    float ng[4] = {0.f, 0.f, 0.f, 0.f};
    if (t + 1 < TT) {
      const int rb = (t+1) >> 7;
      if (rdy <= rb) {
        while (__hip_atomic_load(&cnt[rb], __ATOMIC_ACQUIRE, __HIP_MEMORY_SCOPE_AGENT) < 64) {}
        rdy = rb + 1;
      }
      #pragma unroll
      for (int g = 0; g < 4; ++g)
        ng[g] = gx[(size_t)(t+1)*GH + (g << 10) + o];
    }

    if (t > 0) {
      const unsigned long long* sb = prep + (size_t)(t & 1) * 1024;
      const unsigned tg = (unsigned)t;
      unsigned long long v0 = __hip_atomic_load(&sb[i0], __ATOMIC_RELAXED, __HIP_MEMORY_SCOPE_AGENT);
      unsigned long long v1 = __hip_atomic_load(&sb[i1], __ATOMIC_RELAXED, __HIP_MEMORY_SCOPE_AGENT);
      while ((unsigned)(v0 >> 32) != tg)
        v0 = __hip_atomic_load(&sb[i0], __ATOMIC_RELAXED, __HIP_MEMORY_SCOPE_AGENT);
      while ((unsigned)(v1 >> 32) != tg)
        v1 = __hip_atomic_load(&sb[i1], __ATOMIC_RELAXED, __HIP_MEMORY_SCOPE_AGENT);
      h_lds[p0] = __uint_as_float((unsigned)v0);
      h_lds[p1] = __uint_as_float((unsigned)v1);
      __syncthreads();               // h(t) complete
    }

    // dot: 4 gates of output o; lane s covers h[s*32 .. s*32+31]
    float a0 = 0.f, a1 = 0.f, a2 = 0.f, a3 = 0.f;
    const float* hseg = h_lds + s*HSTRIDE;
    #pragma unroll
    for (int j2 = 0; j2 < 8; ++j2) {
      const float2 hA = *(const float2*)(hseg + 4*j2);
      const float2 hB = *(const float2*)(hseg + 4*j2 + 2);
      const uint2 w0 = wld2[(G*4 + 0)*ROWU + j2*32 + s];
      const uint2 w1 = wld2[(G*4 + 1)*ROWU + j2*32 + s];
      const uint2 w2 = wld2[(G*4 + 2)*ROWU + j2*32 + s];
      const uint2 w3 = wld2[(G*4 + 3)*ROWU + j2*32 + s];
      a0 = fmaf(bflo(w0.x), hA.x, a0); a0 = fmaf(bfhi(w0.x), hA.y, a0);
      a0 = fmaf(bflo(w0.y), hB.x, a0); a0 = fmaf(bfhi(w0.y), hB.y, a0);
      a1 = fmaf(bflo(w1.x), hA.x, a1); a1 = fmaf(bfhi(w1.x), hA.y, a1);
      a1 = fmaf(bflo(w1.y), hB.x, a1); a1 = fmaf(bfhi(w1.y), hB.y, a1);
      a2 = fmaf(bflo(w2.x), hA.x, a2); a2 = fmaf(bfhi(w2.x), hA.y, a2);
      a2 = fmaf(bflo(w2.y), hB.x, a2); a2 = fmaf(bfhi(w2.y), hB.y, a2);
      a3 = fmaf(bflo(w3.x), hA.x, a3); a3 = fmaf(bfhi(w3.x), hA.y, a3);
      a3 = fmaf(bflo(w3.y), hB.x, a3); a3 = fmaf(bfhi(w3.y), hB.y, a3);
    }
    #pragma unroll
    for (int m = 1; m <= 16; m <<= 1) {   // stays within the 32-lane group
      a0 += __shfl_xor(a0, m);
      a1 += __shfl_xor(a1, m);
      a2 += __shfl_xor(a2, m);
      a3 += __shfl_xor(a3, m);
    }

    const float xi = a0 + g4[0];
    const float xf = a1 + g4[1];
    const float xg = a2 + g4[2];
    const float xo = a3 + g4[3];
    cst = sigm(xf)*cst + sigm(xi)*tanhf(xg);
    const float hnew = sigm(xo)*tanhf(cst);

    if (t == TT-1) {
      if (s == 0) {
        out[o]        = hnew;
        out[1024 + o] = cst;
      }
    } else {
      if (s == 0) {                   // publish immediately to all replicas
        const unsigned long long pv =
            (((unsigned long long)(unsigned)(t+1)) << 32) |
            (unsigned long long)__float_as_uint(hnew);
        const int nxt = (t+1) & 1;
        #pragma unroll
        for (int r = 0; r < NREP; ++r)
          __hip_atomic_store(&slots[(size_t)(r*2 + nxt)*1024 + o], pv,
                             __ATOMIC_RELAXED, __HIP_MEMORY_SCOPE_AGENT);
      }
      #pragma unroll
      for (int g = 0; g < 4; ++g) g4[g] = ng[g];
    }
    __syncthreads();                  // protect h_lds before next fill
  }
}

// -------- fallbacks (separate kernels; used only if attribute/ws fails) --------
__global__ __launch_bounds__(256) void gemm_simple(
    const int* __restrict__ tokens,
    const float* __restrict__ emb,
    const float* __restrict__ Wih,
    const float* __restrict__ bih,
    const float* __restrict__ bhh,
    float* __restrict__ gx)
{
  __shared__ float As[BM][BK+1];
  __shared__ float Bs[BN][BK+1];
  __shared__ int tok_s[BM];

  const int tid = threadIdx.x;
  const int bn = blockIdx.x;
  const int bm = blockIdx.y;
  const int m0 = bm*BM, n0 = bn*BN;

  if (tid < BM) tok_s[tid] = tokens[m0 + tid];
  __syncthreads();

  const int tm = tid >> 4;
  const int tn = tid & 15;

  float acc[8][4];
  #pragma unroll
  for (int i = 0; i < 8; ++i)
    #pragma unroll
    for (int j = 0; j < 4; ++j) acc[i][j] = 0.0f;

  for (int k0 = 0; k0 < HH; k0 += BK) {
    for (int idx = tid; idx < BM*BK; idx += 256) {
      int r = idx >> 5, c = idx & 31;
      As[r][c] = emb[(size_t)tok_s[r]*HH + k0 + c];
    }
    for (int idx = tid; idx < BN*BK; idx += 256) {
      int r = idx >> 5, c = idx & 31;
      Bs[r][c] = Wih[(size_t)(n0 + r)*HH + k0 + c];
    }
    __syncthreads();
    #pragma unroll
    for (int k = 0; k < BK; ++k) {
      float a[8], bb[4];
      #pragma unroll
      for (int i = 0; i < 8; ++i) a[i] = As[tm*8 + i][k];
      #pragma unroll
      for (int j = 0; j < 4; ++j) bb[j] = Bs[tn*4 + j][k];
      #pragma unroll
      for (int i = 0; i < 8; ++i)
        #pragma unroll
        for (int j = 0; j < 4; ++j)
          acc[i][j] = fmaf(a[i], bb[j], acc[i][j]);
    }
    __syncthreads();
  }

  float bias[4];
  #pragma unroll
  for (int j = 0; j < 4; ++j) {
    int col = n0 + tn*4 + j;
    bias[j] = bih[col] + bhh[col];
  }
  #pragma unroll
  for (int i = 0; i < 8; ++i) {
    int r = m0 + tm*8 + i;
    #pragma unroll
    for (int j = 0; j < 4; ++j)
      gx[(size_t)r*GH + (n0 + tn*4 + j)] = acc[i][j] + bias[j];
  }
}

__global__ __launch_bounds__(NTH, 2) void lstm_scan_reg(
    const float* __restrict__ gx,
    const float* __restrict__ Whh,
    unsigned long long* slots,
    float* __restrict__ out)
{
  const int b = blockIdx.x;
  const int tid = threadIdx.x;
  const int s  = tid & 31;
  const int rg = tid >> 5;

  __shared__ float h_lds[32*HSTRIDE];
  __shared__ float gates_lds[64];

  float w[128];
  #pragma unroll
  for (int a = 0; a < 4; ++a) {
    int row = rg*4 + a;
    int jrow = ((row >> 4) << 10) + (b << 4) + (row & 15);
    const float* wr = Whh + (size_t)jrow*HH + s*32;
    #pragma unroll
    for (int q = 0; q < 8; ++q) {
      float4 f4 = ((const float4*)wr)[q];
      w[a*32 + q*4 + 0] = f4.x; w[a*32 + q*4 + 1] = f4.y;
      w[a*32 + q*4 + 2] = f4.z; w[a*32 + q*4 + 3] = f4.w;
    }
  }

  for (int i = tid; i < 32*HSTRIDE; i += NTH) h_lds[i] = 0.0f;
  float c0 = 0.0f, c1 = 0.0f;
  const int i0 = tid, i1 = tid + 512;
  const int p0 = (i0 >> 5)*HSTRIDE + (i0 & 31);
  const int p1 = (i1 >> 5)*HSTRIDE + (i1 & 31);
  const int myrow = rg*4 + s;
  const int myj = ((myrow >> 4) << 10) + (b << 4) + (myrow & 15);
  __syncthreads();

  for (int t = 0; t < TT; ++t) {
    float gxv = 0.0f;
    if (s < 4) gxv = gx[(size_t)t*GH + myj];

    if (t > 0) {
      const unsigned long long* sb = slots + (size_t)(t & 1)*1024;
      const unsigned tg = (unsigned)t;
      unsigned long long v0 = __hip_atomic_load(&sb[i0], __ATOMIC_RELAXED, __HIP_MEMORY_SCOPE_AGENT);
      unsigned long long v1 = __hip_atomic_load(&sb[i1], __ATOMIC_RELAXED, __HIP_MEMORY_SCOPE_AGENT);
      while ((unsigned)(v0 >> 32) != tg)
        v0 = __hip_atomic_load(&sb[i0], __ATOMIC_RELAXED, __HIP_MEMORY_SCOPE_AGENT);
      while ((unsigned)(v1 >> 32) != tg)
        v1 = __hip_atomic_load(&sb[i1], __ATOMIC_RELAXED, __HIP_MEMORY_SCOPE_AGENT);
      h_lds[p0] = __uint_as_float((unsigned)v0);
      h_lds[p1] = __uint_as_float((unsigned)v1);
      __syncthreads();
    }

    float acc0 = 0.f, acc1 = 0.f, acc2 = 0.f, acc3 = 0.f;
    const float* hseg = h_lds + s*HSTRIDE;
    #pragma unroll
    for (int c2 = 0; c2 < 16; ++c2) {
      float2 hv = *(const float2*)(hseg + 2*c2);
      acc0 = fmaf(w[0*32+2*c2], hv.x, acc0); acc0 = fmaf(w[0*32+2*c2+1], hv.y, acc0);
      acc1 = fmaf(w[1*32+2*c2], hv.x, acc1); acc1 = fmaf(w[1*32+2*c2+1], hv.y, acc1);
      acc2 = fmaf(w[2*32+2*c2], hv.x, acc2); acc2 = fmaf(w[2*32+2*c2+1], hv.y, acc2);
      acc3 = fmaf(w[3*32+2*c2], hv.x, acc3); acc3 = fmaf(w[3*32+2*c2+1], hv.y, acc3);
    }
    #pragma unroll
    for (int m = 1; m <= 16; m <<= 1) {
      acc0 += __shfl_xor(acc0, m);
      acc1 += __shfl_xor(acc1, m);
      acc2 += __shfl_xor(acc2, m);
      acc3 += __shfl_xor(acc3, m);
    }
    if (s < 4) {
      float v = acc0;
      if (s == 1) v = acc1; else if (s == 2) v = acc2; else if (s == 3) v = acc3;
      gates_lds[rg*4 + s] = v + gxv;
    }
    __syncthreads();

    if (tid < 8) {
      int n0 = tid*2, n1 = n0 + 1;
      float xi0 = gates_lds[n0],    xi1 = gates_lds[n1];
      float xf0 = gates_lds[16+n0], xf1 = gates_lds[16+n1];
      float xg0 = gates_lds[32+n0], xg1 = gates_lds[32+n1];
      float xo0 = gates_lds[48+n0], xo1 = gates_lds[48+n1];
      c0 = sigm(xf0)*c0 + sigm(xi0)*tanhf(xg0);
      c1 = sigm(xf1)*c1 + sigm(xi1)*tanhf(xg1);
      float h0 = sigm(xo0)*tanhf(c0);
      float h1 = sigm(xo1)*tanhf(c1);
      if (t == TT-1) {
        out[(b<<4)+n0]      = h0;
        out[(b<<4)+n1]      = h1;
        out[1024+(b<<4)+n0] = c0;
        out[1024+(b<<4)+n1] = c1;
      } else {
        unsigned long long* db = slots + (size_t)((t+1)&1)*1024;
        unsigned long long tg = ((unsigned long long)(unsigned)(t+1)) << 32;
        __hip_atomic_store(&db[(b<<4)+n0], tg | (unsigned long long)__float_as_uint(h0),
                           __ATOMIC_RELAXED, __HIP_MEMORY_SCOPE_AGENT);
        __hip_atomic_store(&db[(b<<4)+n1], tg | (unsigned long long)__float_as_uint(h1),
                           __ATOMIC_RELAXED, __HIP_MEMORY_SCOPE_AGENT);
      }
    }
  }
}

__global__ void zero_out(float* out){
  int i = blockIdx.x*256 + threadIdx.x;
  if (i < 2048) out[i] = 0.0f;
}

extern "C" void kernel_launch(void* const* d_in, const int* in_sizes, int n_in,
                              void* d_out, int out_size, void* d_ws, size_t ws_size,
                              hipStream_t stream) {
  (void)in_sizes; (void)n_in; (void)out_size;
  const int* tokens = (const int*)d_in[0];
  const float* emb  = (const float*)d_in[1];
  const float* Wih  = (const float*)d_in[2];
  const float* Whh  = (const float*)d_in[3];
  const float* bih  = (const float*)d_in[4];
  const float* bhh  = (const float*)d_in[5];
  float* out = (float*)d_out;

  const size_t gxBytes   = (size_t)TT*GH*sizeof(float);
  const size_t slotBytes = (size_t)NREP*2*1024*8;   // 131072
  const size_t ctrlBytes = slotBytes + 2048;        // + cnt[16] (padded)

  unsigned long long* slots = (unsigned long long*)d_ws;
  int* cnt  = (int*)((char*)d_ws + slotBytes);
  float* gx = (float*)((char*)d_ws + ctrlBytes);

  if (ws_size < ctrlBytes + gxBytes) {
    if (ws_size >= 16384 + gxBytes) {
      float* gx1 = (float*)((char*)d_ws + 16384);
      hipMemsetAsync(d_ws, 0, 16384, stream);
      gemm_simple<<<dim3(64,16), dim3(256), 0, stream>>>(tokens, emb, Wih, bih, bhh, gx1);
      lstm_scan_reg<<<dim3(SCANBLK), dim3(NTH), 0, stream>>>(gx1, Whh, slots, out);
    } else {
      zero_out<<<dim3(8), dim3(256), 0, stream>>>(out);
    }
    return;
  }

  hipMemsetAsync(d_ws, 0, ctrlBytes, stream);

  const int dynBytes = 64 * (2*ROWU) * 4;   // 131584 B (scan weights / gemm tiles overlay)
  hipError_t e = hipFuncSetAttribute((const void*)fused_lstm,
                                     hipFuncAttributeMaxDynamicSharedMemorySize,
                                     dynBytes);
  if (e == hipSuccess) {
    fused_lstm<<<dim3(SCANBLK + GEMMBLK), dim3(NTH), dynBytes, stream>>>(
        tokens, emb, Wih, bih, bhh, Whh, slots, cnt, gx, out);
  } else {
    (void)hipGetLastError();
    gemm_simple<<<dim3(64,16), dim3(256), 0, stream>>>(tokens, emb, Wih, bih, bhh, gx);
    lstm_scan_reg<<<dim3(SCANBLK), dim3(NTH), 0, stream>>>(gx, Whh, slots, out);
  }
}